// Round 1
// baseline (1202.083 us; speedup 1.0000x reference)
//
#include <hip/hip_runtime.h>

#define TT 1024   // timesteps
#define HH 32     // hidden
// batch = 512, handled as 256 blocks x 2 batch elements

__device__ __forceinline__ float fast_sigmoid(float x) {
    // 1 / (1 + 2^(-x*log2(e)))
    float e = __builtin_amdgcn_exp2f(x * -1.4426950408889634f);
    return __builtin_amdgcn_rcpf(1.0f + e);
}
__device__ __forceinline__ float fast_tanh(float x) {
    // 2 / (1 + 2^(-2x*log2(e))) - 1
    float e = __builtin_amdgcn_exp2f(x * -2.8853900817779268f);
    return fmaf(2.0f, __builtin_amdgcn_rcpf(1.0f + e), -1.0f);
}

// 3 simultaneous 32-length dot products (gates r,z,n) against LDS-resident W.
// W layout: chunk-major [k4][row=g*32+h][4], 384 floats per k4 slab.
// Each ds_read_b128: 32 lanes read 32 contiguous 16B chunks (bank-balanced),
// batch halves broadcast.
__device__ __forceinline__ void dot3x32(const float* lds, int wb, int vb, int h4,
                                        float& a0, float& a1, float& a2) {
#pragma unroll
    for (int k4 = 0; k4 < 8; ++k4) {
        const float4 v  = *(const float4*)(lds + vb + k4*4);
        const float4 w0 = *(const float4*)(lds + wb + k4*384 +       h4);
        const float4 w1 = *(const float4*)(lds + wb + k4*384 + 128 + h4);
        const float4 w2 = *(const float4*)(lds + wb + k4*384 + 256 + h4);
        a0 = fmaf(w0.w, v.w, fmaf(w0.z, v.z, fmaf(w0.y, v.y, fmaf(w0.x, v.x, a0))));
        a1 = fmaf(w1.w, v.w, fmaf(w1.z, v.z, fmaf(w1.y, v.y, fmaf(w1.x, v.x, a1))));
        a2 = fmaf(w2.w, v.w, fmaf(w2.z, v.z, fmaf(w2.y, v.y, fmaf(w2.x, v.x, a2))));
    }
}

// LDS float map:
//   [    0) W_hh1   (3072, rearranged)
//   [ 3072) W_ih2   (3072)
//   [ 6144) W_hh2   (3072)
//   [ 9216) W_ih3   (3072)
//   [12288) W_hh3   (3072)
//   [15360) ybuf: 3 layers x [2 parity][2 batch][32]  (384 floats)
// total 15744 floats = 62,976 B (< 64 KB static LDS)
__global__ __launch_bounds__(192) void gru3_fused(
    const float* __restrict__ x,
    const float* __restrict__ Wih1, const float* __restrict__ Whh1,
    const float* __restrict__ bih1, const float* __restrict__ bhh1,
    const float* __restrict__ Wih2, const float* __restrict__ Whh2,
    const float* __restrict__ bih2, const float* __restrict__ bhh2,
    const float* __restrict__ Wih3, const float* __restrict__ Whh3,
    const float* __restrict__ bih3, const float* __restrict__ bhh3,
    float* __restrict__ out)
{
    __shared__ float lds[15744];
    const int tid = threadIdx.x;

    // ---- one-time: stage weights into LDS, chunk-major rearrange ----
    {
        const float* srcs[5] = {Whh1, Wih2, Whh2, Wih3, Whh3};
#pragma unroll
        for (int m = 0; m < 5; ++m) {
            const float* s = srcs[m];
            float* d = lds + m*3072;
            for (int i = tid; i < 3072; i += 192) {
                const int row = i >> 5;       // 0..95 (g*32+h)
                const int k   = i & 31;       // 0..31
                d[(k >> 2)*384 + row*4 + (k & 3)] = s[i];
            }
        }
        for (int i = tid; i < 384; i += 192) lds[15360 + i] = 0.0f;  // h0 = 0
    }

    const int wid  = tid >> 6;        // wave = layer index 0..2
    const int lane = tid & 63;
    const int half = lane >> 5;       // which of the block's 2 batch elems
    const int h    = lane & 31;       // hidden unit
    const int h4   = h * 4;
    const int bb   = 2*(int)blockIdx.x + half;   // global batch index

    // per-wave (per-layer) biases; fold b_ih+b_hh for r,z
    const float* bihp = (wid == 0) ? bih1 : (wid == 1) ? bih2 : bih3;
    const float* bhhp = (wid == 0) ? bhh1 : (wid == 1) ? bhh2 : bhh3;
    const float bias_r  = bihp[h]      + bhhp[h];
    const float bias_z  = bihp[32 + h] + bhhp[32 + h];
    const float bias_in = bihp[64 + h];
    const float bias_hn = bhhp[64 + h];

    const int whh_base = (wid == 0) ? 0 : (wid == 1) ? 6144 : 12288;
    const int wih_base = (wid == 1) ? 3072 : 9216;   // unused for wid==0
    const int own_base = 15360 + wid*128;
    const int in_base  = 15360 + (wid - 1)*128;      // valid for wid>=1

    // layer-1 scalar-input weights + x prefetch
    float wi_r = 0.f, wi_z = 0.f, wi_n = 0.f;
    const float* xrow = x + bb*TT;
    float xv = 0.f;
    if (wid == 0) {
        wi_r = Wih1[h]; wi_z = Wih1[32 + h]; wi_n = Wih1[64 + h];
        xv = xrow[0];
    }

    __syncthreads();

    float hprev = 0.0f;
    // pipelined: at iteration i, wave L computes timestep t = i - L
    for (int i = 0; i < TT + 2; ++i) {
        const int t = i - wid;
        if (t >= 0 && t < TT) {
            const int p = t & 1;
            float ar = bias_r, az = bias_z, ain = bias_in, ahn = bias_hn;
            if (wid == 0) {
                ar  = fmaf(xv, wi_r, ar);
                az  = fmaf(xv, wi_z, az);
                ain = fmaf(xv, wi_n, ain);
                xv = xrow[(t + 1) & (TT - 1)];   // prefetch next x (wraps, in-bounds)
            } else {
                // input projection from previous layer's output at this t
                dot3x32(lds, wih_base, in_base + p*64 + half*32, h4, ar, az, ain);
            }
            // recurrent projection from own h(t-1)
            dot3x32(lds, whh_base, own_base + (p ^ 1)*64 + half*32, h4, ar, az, ahn);

            const float r  = fast_sigmoid(ar);
            const float z  = fast_sigmoid(az);
            const float n  = fast_tanh(fmaf(r, ahn, ain));
            const float hn = fmaf(z, hprev - n, n);
            hprev = hn;
            lds[own_base + p*64 + half*32 + h] = hn;   // publish h(t) (64 consecutive floats)
            if (wid == 2) out[t*16384 + bb*32 + h] = hn;  // out[t][b][h], coalesced
        }
        __syncthreads();
    }
}

extern "C" void kernel_launch(void* const* d_in, const int* in_sizes, int n_in,
                              void* d_out, int out_size, void* d_ws, size_t ws_size,
                              hipStream_t stream) {
    const float* x    = (const float*)d_in[0];
    const float* Wih1 = (const float*)d_in[1];
    const float* Whh1 = (const float*)d_in[2];
    const float* bih1 = (const float*)d_in[3];
    const float* bhh1 = (const float*)d_in[4];
    const float* Wih2 = (const float*)d_in[5];
    const float* Whh2 = (const float*)d_in[6];
    const float* bih2 = (const float*)d_in[7];
    const float* bhh2 = (const float*)d_in[8];
    const float* Wih3 = (const float*)d_in[9];
    const float* Whh3 = (const float*)d_in[10];
    const float* bih3 = (const float*)d_in[11];
    const float* bhh3 = (const float*)d_in[12];

    gru3_fused<<<dim3(256), dim3(192), 0, stream>>>(
        x, Wih1, Whh1, bih1, bhh1,
        Wih2, Whh2, bih2, bhh2,
        Wih3, Whh3, bih3, bhh3,
        (float*)d_out);
}

// Round 4
// 787.115 us; speedup vs baseline: 1.5272x; 1.5272x over previous
//
#include <hip/hip_runtime.h>

#define TT 1024   // timesteps
#define HH 32     // hidden
// batch = 512 sequences, 1 per block; 3 waves/block = 1 per GRU layer.
// Weights live in REGISTERS (per-lane rows, k-split across wave halves).
// Only h-vectors flow through LDS (double-buffered), 1 barrier per step.

__device__ __forceinline__ float fast_sigmoid(float x) {
    float e = __builtin_amdgcn_exp2f(x * -1.4426950408889634f);
    return __builtin_amdgcn_rcpf(1.0f + e);
}
__device__ __forceinline__ float fast_tanh(float x) {
    float e = __builtin_amdgcn_exp2f(x * -2.8853900817779268f);
    return fmaf(2.0f, __builtin_amdgcn_rcpf(1.0f + e), -1.0f);
}

__device__ __forceinline__ void acc3(const float4 w0, const float4 w1, const float4 w2,
                                     const float4 v, float4& a0, float4& a1, float4& a2) {
    a0.x = fmaf(w0.x, v.x, a0.x); a0.y = fmaf(w0.y, v.y, a0.y);
    a0.z = fmaf(w0.z, v.z, a0.z); a0.w = fmaf(w0.w, v.w, a0.w);
    a1.x = fmaf(w1.x, v.x, a1.x); a1.y = fmaf(w1.y, v.y, a1.y);
    a1.z = fmaf(w1.z, v.z, a1.z); a1.w = fmaf(w1.w, v.w, a1.w);
    a2.x = fmaf(w2.x, v.x, a2.x); a2.y = fmaf(w2.y, v.y, a2.y);
    a2.z = fmaf(w2.z, v.z, a2.z); a2.w = fmaf(w2.w, v.w, a2.w);
}
__device__ __forceinline__ float hsum(const float4 a) {
    return (a.x + a.y) + (a.z + a.w);
}

__global__ __launch_bounds__(192) void gru3_fused(
    const float* __restrict__ x,
    const float* __restrict__ Wih1, const float* __restrict__ Whh1,
    const float* __restrict__ bih1, const float* __restrict__ bhh1,
    const float* __restrict__ Wih2, const float* __restrict__ Whh2,
    const float* __restrict__ bih2, const float* __restrict__ bhh2,
    const float* __restrict__ Wih3, const float* __restrict__ Whh3,
    const float* __restrict__ bih3, const float* __restrict__ bhh3,
    float* __restrict__ out)
{
    __shared__ float ybuf[3 * 2 * 32];   // [layer][parity][h]
    __shared__ float xs[TT];             // staged x row for this batch elem

    const int tid  = threadIdx.x;
    const int wid  = tid >> 6;        // wave = layer 0..2
    const int lane = tid & 63;
    const int h    = lane & 31;       // hidden unit (each h owned by 2 lanes)
    const int kh   = lane >> 5;       // k-half: lanes 0-31 -> k 0..15, 32-63 -> k 16..31
    const int k0   = kh * 16;
    const int bb   = (int)blockIdx.x; // batch index 0..511

    // ---- one-time staging ----
    if (tid < 192) ybuf[tid] = 0.0f;                       // h0 = 0 (both parities)
    {
        const float4* xr4 = (const float4*)(x + bb * TT);
        for (int j = tid; j < TT / 4; j += 192) ((float4*)xs)[j] = xr4[j];
    }

    // ---- per-lane register weights ----
    const float* Whh = (wid == 0) ? Whh1 : (wid == 1) ? Whh2 : Whh3;
    float4 whh[3][4];
#pragma unroll
    for (int g = 0; g < 3; ++g)
#pragma unroll
        for (int j = 0; j < 4; ++j)
            whh[g][j] = *(const float4*)(Whh + (g * 32 + h) * 32 + k0 + 4 * j);

    float4 wih[3][4];
    float wi_r = 0.f, wi_z = 0.f, wi_n = 0.f;
    if (wid == 0) {
        wi_r = Wih1[h]; wi_z = Wih1[32 + h]; wi_n = Wih1[64 + h];
#pragma unroll
        for (int g = 0; g < 3; ++g)
#pragma unroll
            for (int j = 0; j < 4; ++j)
                wih[g][j] = make_float4(0.f, 0.f, 0.f, 0.f);
    } else {
        const float* Wih = (wid == 1) ? Wih2 : Wih3;
#pragma unroll
        for (int g = 0; g < 3; ++g)
#pragma unroll
            for (int j = 0; j < 4; ++j)
                wih[g][j] = *(const float4*)(Wih + (g * 32 + h) * 32 + k0 + 4 * j);
    }

    const float* bihp = (wid == 0) ? bih1 : (wid == 1) ? bih2 : bih3;
    const float* bhhp = (wid == 0) ? bhh1 : (wid == 1) ? bhh2 : bhh3;
    const float brz_r = bihp[h]      + bhhp[h];
    const float brz_z = bihp[32 + h] + bhhp[32 + h];
    const float b_in  = bihp[64 + h];
    const float b_hn  = bhhp[64 + h];

    __syncthreads();

    float hprev = 0.0f;
    // pipelined: at iteration i, wave L computes timestep t = i - L
    for (int i = 0; i < TT + 2; ++i) {
        const int t = i - wid;
        if (t >= 0 && t < TT) {
            const int p = t & 1;

            // own h(t-1): 4 broadcast b128 reads (per half)
            const float4* vop = (const float4*)(ybuf + wid * 64 + (p ^ 1) * 32 + k0);
            const float4 vo0 = vop[0], vo1 = vop[1], vo2 = vop[2], vo3 = vop[3];

            float4 a0 = make_float4(0.f, 0.f, 0.f, 0.f), a1 = a0, a2 = a0;
            acc3(whh[0][0], whh[1][0], whh[2][0], vo0, a0, a1, a2);
            acc3(whh[0][1], whh[1][1], whh[2][1], vo1, a0, a1, a2);
            acc3(whh[0][2], whh[1][2], whh[2][2], vo2, a0, a1, a2);
            acc3(whh[0][3], whh[1][3], whh[2][3], vo3, a0, a1, a2);
            float shr = hsum(a0), shz = hsum(a1), shn = hsum(a2);

            float pir, piz, pin;
            if (wid == 0) {
                const float xv = xs[t];
                pir = xv * wi_r; piz = xv * wi_z; pin = xv * wi_n;
            } else {
                const float4* vip = (const float4*)(ybuf + (wid - 1) * 64 + p * 32 + k0);
                const float4 vi0 = vip[0], vi1 = vip[1], vi2 = vip[2], vi3 = vip[3];
                float4 b0 = make_float4(0.f, 0.f, 0.f, 0.f), b1 = b0, b2 = b0;
                acc3(wih[0][0], wih[1][0], wih[2][0], vi0, b0, b1, b2);
                acc3(wih[0][1], wih[1][1], wih[2][1], vi1, b0, b1, b2);
                acc3(wih[0][2], wih[1][2], wih[2][2], vi2, b0, b1, b2);
                acc3(wih[0][3], wih[1][3], wih[2][3], vi3, b0, b1, b2);
                pir = hsum(b0); piz = hsum(b1); pin = hsum(b2);
                // input-projection partial sums need the cross-half reduce too
                pir += __shfl_xor(pir, 32);
                piz += __shfl_xor(piz, 32);
                pin += __shfl_xor(pin, 32);
            }
            // recurrent partial sums: combine the two k-halves
            shr += __shfl_xor(shr, 32);
            shz += __shfl_xor(shz, 32);
            shn += __shfl_xor(shn, 32);

            const float r  = fast_sigmoid(pir + shr + brz_r);
            const float z  = fast_sigmoid(piz + shz + brz_z);
            const float n  = fast_tanh(fmaf(r, shn + b_hn, pin + b_in));
            const float hn = fmaf(z, hprev - n, n);
            hprev = hn;

            if (kh == 0) {
                ybuf[wid * 64 + p * 32 + h] = hn;            // publish h(t)
                if (wid == 2) out[t * 16384 + bb * 32 + h] = hn;  // [T,B,H] flat
            }
        }
        __syncthreads();
    }
}

extern "C" void kernel_launch(void* const* d_in, const int* in_sizes, int n_in,
                              void* d_out, int out_size, void* d_ws, size_t ws_size,
                              hipStream_t stream) {
    const float* x    = (const float*)d_in[0];
    const float* Wih1 = (const float*)d_in[1];
    const float* Whh1 = (const float*)d_in[2];
    const float* bih1 = (const float*)d_in[3];
    const float* bhh1 = (const float*)d_in[4];
    const float* Wih2 = (const float*)d_in[5];
    const float* Whh2 = (const float*)d_in[6];
    const float* bih2 = (const float*)d_in[7];
    const float* bhh2 = (const float*)d_in[8];
    const float* Wih3 = (const float*)d_in[9];
    const float* Whh3 = (const float*)d_in[10];
    const float* bih3 = (const float*)d_in[11];
    const float* bhh3 = (const float*)d_in[12];

    gru3_fused<<<dim3(512), dim3(192), 0, stream>>>(
        x, Wih1, Whh1, bih1, bhh1,
        Wih2, Whh2, bih2, bhh2,
        Wih3, Whh3, bih3, bhh3,
        (float*)d_out);
}